// Round 16
// baseline (1114.818 us; speedup 1.0000x reference)
//
#include <hip/hip_runtime.h>
#include <hip/hip_bf16.h>
#include <math.h>

// Problem constants
constexpr int V  = 32000;
constexpr int D  = 400;
constexpr int L  = 6;
constexpr int H  = 8;
constexpr int FF = 1600;
constexpr int B  = 2;
constexpr int N  = 2048;
constexpr int HD = D / H;      // 50
constexpr int TD = 3 * D;      // 1200
constexpr int M  = B * N;      // 4096 rows
constexpr int KP = 416;        // K=400 padded to multiple of 32

typedef __bf16 bf16x8 __attribute__((ext_vector_type(8)));
typedef float  f32x4  __attribute__((ext_vector_type(4)));
typedef unsigned short us16x4 __attribute__((ext_vector_type(4)));

static __device__ __forceinline__ float wave_sum_f(float v) {
#pragma unroll
    for (int m = 32; m; m >>= 1) v += __shfl_xor(v, m, 64);
    return v;
}

static __device__ __forceinline__ void gl_lds16(const unsigned short* g, unsigned short* l) {
    __builtin_amdgcn_global_load_lds(
        (const __attribute__((address_space(1))) unsigned int*)(g),
        (__attribute__((address_space(3))) unsigned int*)(l), 16, 0, 0);
}

static __device__ __forceinline__ unsigned short f2bf(float f) {
    __hip_bfloat16 h = __float2bfloat16(f);
    return *reinterpret_cast<unsigned short*>(&h);
}

// ---------------- embedding + ln1(layer0) fused: writes x fp32 and hb bf16[KP] ----------------
__global__ __launch_bounds__(256) void embed_ln_kernel(const int* __restrict__ idx,
                                                       const float* __restrict__ tok,
                                                       const float* __restrict__ pos,
                                                       const float* __restrict__ lnw,
                                                       const float* __restrict__ lnb,
                                                       float* __restrict__ x,
                                                       __hip_bfloat16* __restrict__ hb) {
    const int row  = blockIdx.x * 4 + (threadIdx.x >> 6);
    const int lane = threadIdx.x & 63;
    const int n = row & (N - 1);
    const float* tr = tok + (size_t)idx[row] * D;
    const float* pr = pos + (size_t)n * D;

    float v[7];
    float s = 0.f, ss = 0.f;
#pragma unroll
    for (int i = 0; i < 7; ++i) {
        const int d = lane + i * 64;
        if (d < D) {
            v[i] = tr[d] + pr[d];
            s += v[i]; ss += v[i] * v[i];
        } else v[i] = 0.f;
    }
    s  = wave_sum_f(s);
    ss = wave_sum_f(ss);
    const float mean = s * (1.0f / D);
    const float var  = ss * (1.0f / D) - mean * mean;
    const float rstd = rsqrtf(var + 1e-5f);

    float* xr = x + (size_t)row * D;
    __hip_bfloat16* hr = hb + (size_t)row * KP;
#pragma unroll
    for (int i = 0; i < 7; ++i) {
        const int d = lane + i * 64;
        if (d < D) {
            xr[d] = v[i];
            hr[d] = __float2bfloat16((v[i] - mean) * rstd * lnw[d] + lnb[d]);
        } else if (d < KP) {
            hr[d] = __float2bfloat16(0.f);
        }
    }
}

// ---------------- LayerNorm fp32 -> bf16 [row][KP] zero-padded; 4 rows/block ----------------
__global__ __launch_bounds__(256) void ln_bf16_kernel(const float* __restrict__ in,
                                                      const float* __restrict__ w,
                                                      const float* __restrict__ b,
                                                      __hip_bfloat16* __restrict__ out) {
    const int row  = blockIdx.x * 4 + (threadIdx.x >> 6);
    const int lane = threadIdx.x & 63;
    const float* xr = in + (size_t)row * D;
    float s = 0.f, ss = 0.f;
    for (int d = lane; d < D; d += 64) {
        float v = xr[d];
        s += v; ss += v * v;
    }
    s  = wave_sum_f(s);
    ss = wave_sum_f(ss);
    float mean = s * (1.0f / D);
    float var  = ss * (1.0f / D) - mean * mean;
    float rstd = rsqrtf(var + 1e-5f);
    __hip_bfloat16* orow = out + (size_t)row * KP;
    for (int d = lane; d < KP; d += 64)
        orow[d] = __float2bfloat16(d < D ? (xr[d] - mean) * rstd * w[d] + b[d] : 0.f);
}

// ---------------- unified weight transpose + fp32->bf16 for the 4 layer-weight tensors ----------------
__global__ __launch_bounds__(256) void wconv_all_kernel(const float* __restrict__ qkv_w,
                                                        const float* __restrict__ ao_w,
                                                        const float* __restrict__ fc1_w,
                                                        const float* __restrict__ fc2_w,
                                                        __hip_bfloat16* __restrict__ qkvt,
                                                        __hip_bfloat16* __restrict__ aot,
                                                        __hip_bfloat16* __restrict__ fc1t,
                                                        __hip_bfloat16* __restrict__ fc2t) {
    const int bid = blockIdx.x;
    int t, rem;
    if      (bid < 3120) { t = 0; rem = bid; }          // qkv: 6 * 13*40
    else if (bid < 4368) { t = 1; rem = bid - 3120; }   // ao : 6 * 13*16
    else if (bid < 8424) { t = 2; rem = bid - 4368; }   // fc1: 6 * 13*52
    else                 { t = 3; rem = bid - 8424; }   // fc2: 6 * 50*16
    const int  tilesPerL[4] = {520, 208, 676, 800};
    const int  nkt[4]  = {13, 13, 13, 50};
    const int  Ka[4]   = {400, 400, 400, 1600};
    const int  Nwa[4]  = {1200, 400, 1600, 400};
    const int  Kpa[4]  = {416, 416, 416, 1600};
    const int  Nra[4]  = {1280, 512, 1664, 512};
    const long sWa[4]  = {480000L, 160000L, 640000L, 640000L};
    const long sBta[4] = {532480L, 212992L, 692224L, 819200L};
    const float* W = t == 0 ? qkv_w : t == 1 ? ao_w : t == 2 ? fc1_w : fc2_w;
    __hip_bfloat16* Bt = t == 0 ? qkvt : t == 1 ? aot : t == 2 ? fc1t : fc2t;
    const int l = rem / tilesPerL[t];
    const int tile = rem % tilesPerL[t];
    const int k0 = (tile % nkt[t]) * 32, n0 = (tile / nkt[t]) * 32;
    const int K = Ka[t], Nw = Nwa[t], Kp = Kpa[t], Nr = Nra[t];

    __shared__ float tt[32][33];
    const float* Wl = W + (size_t)l * sWa[t];
    __hip_bfloat16* Btl = Bt + (size_t)l * sBta[t];
    for (int i = 0; i < 32; i += 8) {
        int k = k0 + threadIdx.y + i, n = n0 + threadIdx.x;
        tt[threadIdx.y + i][threadIdx.x] = (k < K && n < Nw) ? Wl[(size_t)k * Nw + n] : 0.f;
    }
    __syncthreads();
    for (int i = 0; i < 32; i += 8) {
        int n = n0 + threadIdx.y + i, k = k0 + threadIdx.x;
        if (n < Nr && k < Kp) Btl[(size_t)n * Kp + k] = __float2bfloat16(tt[threadIdx.x][threadIdx.y + i]);
    }
}

// ---------------- single-tensor weight transpose (head weight) ----------------
__global__ __launch_bounds__(256) void wconv_kernel(const float* __restrict__ W,
                                                    __hip_bfloat16* __restrict__ Bt,
                                                    int K, int Nw, int Kp, int Nr) {
    __shared__ float t[32][33];
    const int k0 = blockIdx.x * 32, n0 = blockIdx.y * 32;
    for (int i = 0; i < 32; i += 8) {
        int k = k0 + threadIdx.y + i, n = n0 + threadIdx.x;
        t[threadIdx.y + i][threadIdx.x] = (k < K && n < Nw) ? W[(size_t)k * Nw + n] : 0.f;
    }
    __syncthreads();
    for (int i = 0; i < 32; i += 8) {
        int n = n0 + threadIdx.y + i, k = k0 + threadIdx.x;
        if (n < Nr && k < Kp) Bt[(size_t)n * Kp + k] = __float2bfloat16(t[threadIdx.x][threadIdx.y + i]);
    }
}

// ---------------- head GEMM: A-resident LDS (52 KiB -> 3 blocks/CU), zero-barrier K-loop ----
// R15 change: LDS stride 424 -> 416 shorts. 54.3KB capped residency at 2 blocks/CU (the
// latency-bound symptom: MfmaUtil 14%, occ 20%); 52KiB exactly fits 3 blocks/CU (156<=160KiB)
// -> 3 waves/SIMD of TLP. Cost: stride 832B => 8-way bank conflict on the 2 per-step A-reads
// (~70cy, LDS unit, overlaps MFMA pipe) -- net positive if occupancy moves.
__global__ __launch_bounds__(256) void mmhead_kernel(const unsigned short* __restrict__ A,
                                                     const unsigned short* __restrict__ Bt,
                                                     float* __restrict__ C) {
    __shared__ __align__(1024) unsigned short As[64 * 416];   // 52 KiB exactly
    const int tid = threadIdx.x, lane = tid & 63, wid = tid >> 6;
    const int wr = wid >> 1, wc = wid & 1;
    const int l15 = lane & 15, g = lane >> 4;

    const int f   = blockIdx.y * 64 + blockIdx.x;   // 0..1599
    const int swz = (f & 7) * 200 + (f >> 3);       // bijective (1600/8=200)
    const int by  = swz & 63;                       // row tile (fast within XCD chunk)
    const int pg  = swz >> 6;                       // panel group 0..24

    // ---- stage A once (coalesced 16B chunks) ----
    const unsigned short* Ab = A + (size_t)(by * 64) * KP;
    for (int i = tid; i < 64 * 52; i += 256) {
        const int r = i / 52, c = (i % 52) * 8;
        *(bf16x8*)(As + r * 416 + c) = *(const bf16x8*)(Ab + (size_t)r * KP + c);
    }
    __syncthreads();

    const unsigned short* A0 = As + (wr * 32 + l15) * 416 + g * 8;
    const unsigned short* A1 = A0 + 16 * 416;

#pragma unroll
    for (int p = 0; p < 5; ++p) {
        const int col0 = (pg * 5 + p) * 256 + wc * 128;
        const unsigned short* Bc = Bt + (size_t)col0 * KP + g * 8;
        f32x4 acc[2][8] = {};
#pragma unroll
        for (int ks = 0; ks < 13; ++ks) {
            const int k0 = ks * 32;
            bf16x8 b[8];
#pragma unroll
            for (int n = 0; n < 8; ++n)
                b[n] = *(const bf16x8*)(Bc + (size_t)(n * 16 + l15) * KP + k0);
            const bf16x8 a0 = *(const bf16x8*)(A0 + k0);
            const bf16x8 a1 = *(const bf16x8*)(A1 + k0);
#pragma unroll
            for (int n = 0; n < 8; ++n) {
                acc[0][n] = __builtin_amdgcn_mfma_f32_16x16x32_bf16(a0, b[n], acc[0][n], 0, 0, 0);
                acc[1][n] = __builtin_amdgcn_mfma_f32_16x16x32_bf16(a1, b[n], acc[1][n], 0, 0, 0);
            }
        }
        // ---- store this panel (nontemporal: don't evict B from L2) ----
        const int rowb = by * 64 + wr * 32 + (g << 2);
#pragma unroll
        for (int n = 0; n < 8; ++n) {
            const int col = col0 + n * 16 + l15;
#pragma unroll
            for (int m = 0; m < 2; ++m)
#pragma unroll
                for (int r = 0; r < 4; ++r)
                    __builtin_nontemporal_store(acc[m][n][r], &C[(size_t)(rowb + m * 16 + r) * V + col]);
        }
    }
}

// ---------------- bf16 MFMA GEMM (64x128): small-N GEMMs -> fine-grained grids ----------------
template <bool BIAS, bool RES, bool GELU, bool OUTBF>
__global__ __launch_bounds__(256) void mm64_kernel(const unsigned short* __restrict__ A,
                                                   const unsigned short* __restrict__ Bt,
                                                   const float* __restrict__ bias,
                                                   const float* __restrict__ res,
                                                   void* __restrict__ Cv,
                                                   int Nc, int Kp) {
    __shared__ __align__(1024) unsigned short As[64 * 32];
    __shared__ __align__(1024) unsigned short Bs[128 * 32];
    const int tid  = threadIdx.x;
    const int lane = tid & 63, wid = tid >> 6;
    const int wr = wid >> 1, wc = wid & 1;
    const int bx = blockIdx.x, by = blockIdx.y;
    const int l15 = lane & 15, g = lane >> 4;

    f32x4 acc[2][4] = {};

    const unsigned short* Abase = A  + (size_t)(by * 64) * Kp;
    const unsigned short* Bbase = Bt + (size_t)(bx * 128) * Kp;
    const int lrow = lane >> 2;
    const int lcol = (lane & 3) * 8;

    for (int k0 = 0; k0 < Kp; k0 += 32) {
        gl_lds16(Abase + (size_t)(wid * 16 + lrow) * Kp + k0 + lcol, As + wid * 512);
#pragma unroll
        for (int c = 0; c < 2; ++c) {
            const int chunk = wid * 2 + c;
            gl_lds16(Bbase + (size_t)(chunk * 16 + lrow) * Kp + k0 + lcol, Bs + chunk * 512);
        }
        __syncthreads();
        bf16x8 a[2], b[4];
#pragma unroll
        for (int m = 0; m < 2; ++m)
            a[m] = *(const bf16x8*)(As + (wr * 32 + m * 16 + l15) * 32 + g * 8);
#pragma unroll
        for (int n = 0; n < 4; ++n)
            b[n] = *(const bf16x8*)(Bs + (wc * 64 + n * 16 + l15) * 32 + g * 8);
#pragma unroll
        for (int m = 0; m < 2; ++m)
#pragma unroll
            for (int n = 0; n < 4; ++n)
                acc[m][n] = __builtin_amdgcn_mfma_f32_16x16x32_bf16(a[m], b[n], acc[m][n], 0, 0, 0);
        __syncthreads();
    }

    const int col_base = bx * 128 + wc * 64 + l15;
    const int row_base = by * 64 + wr * 32 + (g << 2);
#pragma unroll
    for (int n = 0; n < 4; ++n) {
        const int col = col_base + n * 16;
        if (col >= Nc) continue;
        const float bv = BIAS ? bias[col] : 0.f;
#pragma unroll
        for (int m = 0; m < 2; ++m) {
#pragma unroll
            for (int r = 0; r < 4; ++r) {
                const int row = row_base + m * 16 + r;
                float v = acc[m][n][r] + bv;
                if (GELU) v = 0.5f * v * (1.0f + erff(v * 0.70710678118654752f));
                const size_t ci = (size_t)row * Nc + col;
                if (RES) v += res[ci];
                if (OUTBF) ((__hip_bfloat16*)Cv)[ci] = __float2bfloat16(v);
                else       ((float*)Cv)[ci] = v;
            }
        }
    }
}

// ---------------- qkv GEMM with fused reformat epilogue ----------------
__global__ __launch_bounds__(256) void mm_qkv_kernel(const unsigned short* __restrict__ A,
                                                     const unsigned short* __restrict__ Bt,
                                                     const float* __restrict__ bias,
                                                     unsigned short* __restrict__ Qb,
                                                     unsigned short* __restrict__ Kb,
                                                     unsigned short* __restrict__ Vt) {
    __shared__ __align__(1024) unsigned short As[128 * 32];
    __shared__ __align__(1024) unsigned short Bs[128 * 32];
    const int tid  = threadIdx.x;
    const int lane = tid & 63, wid = tid >> 6;
    const int wr = wid >> 1, wc = wid & 1;
    const int bx = blockIdx.x, by = blockIdx.y;

    f32x4 acc[4][4] = {};

    const unsigned short* Abase = A  + (size_t)(by * 128) * KP;
    const unsigned short* Bbase = Bt + (size_t)(bx * 128) * KP;
    const int lrow = lane >> 2;
    const int lcol = (lane & 3) * 8;

    for (int k0 = 0; k0 < KP; k0 += 32) {
#pragma unroll
        for (int c = 0; c < 2; ++c) {
            const int chunk = wid * 2 + c;
            gl_lds16(Abase + (size_t)(chunk * 16 + lrow) * KP + k0 + lcol, As + chunk * 512);
            gl_lds16(Bbase + (size_t)(chunk * 16 + lrow) * KP + k0 + lcol, Bs + chunk * 512);
        }
        __syncthreads();
        bf16x8 a[4], b[4];
#pragma unroll
        for (int m = 0; m < 4; ++m)
            a[m] = *(const bf16x8*)(As + (wr * 64 + m * 16 + (lane & 15)) * 32 + (lane >> 4) * 8);
#pragma unroll
        for (int n = 0; n < 4; ++n)
            b[n] = *(const bf16x8*)(Bs + (wc * 64 + n * 16 + (lane & 15)) * 32 + (lane >> 4) * 8);
#pragma unroll
        for (int m = 0; m < 4; ++m)
#pragma unroll
            for (int n = 0; n < 4; ++n)
                acc[m][n] = __builtin_amdgcn_mfma_f32_16x16x32_bf16(a[m], b[n], acc[m][n], 0, 0, 0);
        __syncthreads();
    }

    const float scale = 0.14142135623730950f;  // 1/sqrt(50)
    const int col_base = bx * 128 + wc * 64 + (lane & 15);
    const int row_base = by * 128 + wr * 64 + ((lane >> 4) << 2);
#pragma unroll
    for (int n = 0; n < 4; ++n) {
        const int col = col_base + n * 16;
        if (col >= TD) continue;
        const int part = col < D ? 0 : (col < 2 * D ? 1 : 2);
        const int cc = col - part * D;
        const int h = cc / HD, d = cc % HD;
        const float bv = bias[col];
#pragma unroll
        for (int m = 0; m < 4; ++m) {
            const int row0 = row_base + m * 16;          // multiple of 4, no b-crossing
            const int b = row0 >> 11, nn0 = row0 & (N - 1);
            const int bh = b * H + h;
            if (part == 2) {
                us16x4 pk;
#pragma unroll
                for (int r = 0; r < 4; ++r) pk[r] = f2bf(acc[m][n][r] + bv);
                *(us16x4*)(Vt + (size_t)(bh * 64 + d) * N + nn0) = pk;   // 8B packed store
            } else if (part == 0) {
#pragma unroll
                for (int r = 0; r < 4; ++r)
                    Qb[(size_t)(bh * N + nn0 + r) * 64 + d] = f2bf((acc[m][n][r] + bv) * scale);
            } else {
#pragma unroll
                for (int r = 0; r < 4; ++r)
                    Kb[(size_t)(bh * N + nn0 + r) * 64 + d] = f2bf(acc[m][n][r] + bv);
            }
        }
    }
}

// ---------------- MFMA flash attention: LDS-staged K/V, double-buffered, fixed-max softmax ----------------
__global__ __launch_bounds__(256) void fattn_kernel(const unsigned short* __restrict__ Qb,
                                                    const unsigned short* __restrict__ Kb,
                                                    const unsigned short* __restrict__ Vt,
                                                    __hip_bfloat16* __restrict__ o) {
    const int q0 = blockIdx.x * 64, h = blockIdx.y, b = blockIdx.z;
    const int bh = b * H + h;
    const int tid = threadIdx.x, lane = tid & 63, w = tid >> 6;
    const int l15 = lane & 15, g = lane >> 4;

    __shared__ __align__(1024) unsigned short Ks[2][64 * 64];
    __shared__ __align__(1024) unsigned short Vs[2][64 * 64];
    __shared__ __hip_bfloat16 P_s[4][16 * 72];
    unsigned short* Pw = (unsigned short*)&P_s[w][0];

    const int st_r    = (lane >> 3);
    const int st_cblk = (lane ^ (lane >> 3)) & 7;

    const unsigned short* Qrow = Qb + ((size_t)(bh * N + q0 + w * 16 + l15)) * 64 + g * 8;
    const bf16x8 qa0 = *(const bf16x8*)(Qrow);
    const bf16x8 qa1 = *(const bf16x8*)(Qrow + 32);

    f32x4 acc[4] = {};
    float ssum[4] = {0.f, 0.f, 0.f, 0.f};

    const int nt = q0 / 64 + 1;

#define STAGE(buf, j0)                                                                     \
    {                                                                                      \
        _Pragma("unroll")                                                                  \
        for (int c = 0; c < 2; ++c) {                                                      \
            const int rr = (w * 2 + c) * 8 + st_r;                                         \
            gl_lds16(Kb + (size_t)(bh * N + (j0) + rr) * 64 + st_cblk * 8,                 \
                     &Ks[buf][(w * 2 + c) * 512]);                                         \
            gl_lds16(Vt + (size_t)(bh * 64 + rr) * N + (j0) + st_cblk * 8,                 \
                     &Vs[buf][(w * 2 + c) * 512]);                                         \
        }                                                                                  \
    }

    STAGE(0, 0);
    __syncthreads();

    for (int t = 0; t < nt; ++t) {
        const int cur = t & 1;
        if (t + 1 < nt) STAGE(cur ^ 1, (t + 1) * 64);

        f32x4 s[4];
        const int swz = ((l15 & 7) << 3);
#pragma unroll
        for (int n = 0; n < 4; ++n) {
            const unsigned short* kbase = &Ks[cur][(n * 16 + l15) * 64];
            bf16x8 k0 = *(const bf16x8*)(kbase + ((g * 8) ^ swz));
            bf16x8 k1 = *(const bf16x8*)(kbase + (((g + 4) * 8) ^ swz));
            f32x4 z = {};
            z    = __builtin_amdgcn_mfma_f32_16x16x32_bf16(qa0, k0, z, 0, 0, 0);
            s[n] = __builtin_amdgcn_mfma_f32_16x16x32_bf16(qa1, k1, z, 0, 0, 0);
        }
        if (t == nt - 1) {
#pragma unroll
            for (int n = 0; n < 4; ++n)
#pragma unroll
                for (int r = 0; r < 4; ++r)
                    if (l15 + n * 16 > w * 16 + g * 4 + r) s[n][r] = -INFINITY;
        }
#pragma unroll
        for (int n = 0; n < 4; ++n)
#pragma unroll
            for (int r = 0; r < 4; ++r) {
                float p = __expf(s[n][r]);       // masked -> 0
                ssum[r] += p;
                Pw[(g * 4 + r) * 72 + l15 + n * 16] = f2bf(p);
            }
        bf16x8 pa0 = *(const bf16x8*)(Pw + l15 * 72 + g * 8);
        bf16x8 pa1 = *(const bf16x8*)(Pw + l15 * 72 + 32 + g * 8);

#pragma unroll
        for (int n = 0; n < 4; ++n) {
            const unsigned short* vbase = &Vs[cur][(n * 16 + l15) * 64];
            bf16x8 v0 = *(const bf16x8*)(vbase + ((g * 8) ^ swz));
            bf16x8 v1 = *(const bf16x8*)(vbase + (((g + 4) * 8) ^ swz));
            acc[n] = __builtin_amdgcn_mfma_f32_16x16x32_bf16(pa0, v0, acc[n], 0, 0, 0);
            acc[n] = __builtin_amdgcn_mfma_f32_16x16x32_bf16(pa1, v1, acc[n], 0, 0, 0);
        }

        __syncthreads();
    }
#undef STAGE

#pragma unroll
    for (int r = 0; r < 4; ++r)
#pragma unroll
        for (int msk = 1; msk < 16; msk <<= 1) ssum[r] += __shfl_xor(ssum[r], msk, 64);

#pragma unroll
    for (int n = 0; n < 4; ++n) {
        const int d = n * 16 + l15;
        if (d < HD) {
#pragma unroll
            for (int r = 0; r < 4; ++r) {
                const int row = b * N + q0 + w * 16 + g * 4 + r;
                o[(size_t)row * KP + h * HD + d] = __float2bfloat16(acc[n][r] / ssum[r]);
            }
        }
    }
}

// ---------------- launch ----------------
extern "C" void kernel_launch(void* const* d_in, const int* in_sizes, int n_in,
                              void* d_out, int out_size, void* d_ws, size_t ws_size,
                              hipStream_t stream) {
    const int*   idx        = (const int*)d_in[0];
    const float* tok_emb    = (const float*)d_in[1];
    const float* pos_emb    = (const float*)d_in[2];
    const float* ln1_w      = (const float*)d_in[3];
    const float* ln1_b      = (const float*)d_in[4];
    const float* qkv_w      = (const float*)d_in[5];
    const float* qkv_b      = (const float*)d_in[6];
    const float* attn_out_w = (const float*)d_in[7];
    const float* attn_out_b = (const float*)d_in[8];
    const float* ln2_w      = (const float*)d_in[9];
    const float* ln2_b      = (const float*)d_in[10];
    const float* fc1_w      = (const float*)d_in[11];
    const float* fc1_b      = (const float*)d_in[12];
    const float* fc2_w      = (const float*)d_in[13];
    const float* fc2_b      = (const float*)d_in[14];
    const float* lnf_w      = (const float*)d_in[15];
    const float* lnf_b      = (const float*)d_in[16];
    const float* head_w     = (const float*)d_in[17];
    float* out = (float*)d_out;

    // ---- workspace carve-up (bytes) ----
    char* ws = (char*)d_ws;
    __hip_bfloat16* hb   = (__hip_bfloat16*)(ws);                       // [M][KP] bf16   3,407,872
    float*          x    = (float*)(ws + 3407872);                      // [M][D]  fp32   6,553,600
    __hip_bfloat16* ff   = (__hip_bfloat16*)(ws + 9961472);             // [M][FF] bf16  13,107,200
    __hip_bfloat16* ob   = (__hip_bfloat16*)(ws + 23068672);            // [M][KP] bf16   3,407,872
    __hip_bfloat16* headt = (__hip_bfloat16*)(ws + 3407872);            // [V][KP] bf16 aliases x/ff/ob

    // stash region in d_out (rewritten every call; head GEMM overwrites at the end)
    char* wout = (char*)d_out;
    __hip_bfloat16* qkvt = (__hip_bfloat16*)(wout);                     // 6,389,760
    __hip_bfloat16* aot  = (__hip_bfloat16*)(wout + 6389760);           // 2,555,904
    __hip_bfloat16* fc1t = (__hip_bfloat16*)(wout + 8945664);           // 8,306,688
    __hip_bfloat16* fc2t = (__hip_bfloat16*)(wout + 17252352);          // 9,830,400
    unsigned short* qb_g = (unsigned short*)(wout + 27082752);          // 4,194,304
    unsigned short* kb_g = (unsigned short*)(wout + 31277056);          // 4,194,304
    unsigned short* vt_g = (unsigned short*)(wout + 35471360);          // 4,194,304

    // all layer-weight converts in ONE dispatch
    wconv_all_kernel<<<dim3(13224), dim3(32, 8), 0, stream>>>(
        qkv_w, attn_out_w, fc1_w, fc2_w, qkvt, aot, fc1t, fc2t);

    // embedding + ln1(layer0) fused
    embed_ln_kernel<<<dim3(M / 4), dim3(256), 0, stream>>>(idx, tok_emb, pos_emb, ln1_w, ln1_b, x, hb);
    // pad lanes (d in [50,64)) of Qb/Kb/Vt and pad cols of ob must be zero each call
    hipMemsetAsync(ob, 0, (size_t)M * KP * sizeof(__hip_bfloat16), stream);
    hipMemsetAsync(qb_g, 0, 3 * 4194304, stream);

    for (int l = 0; l < L; ++l) {
        mm_qkv_kernel<<<dim3(10, 32), dim3(256), 0, stream>>>(
            (const unsigned short*)hb, (const unsigned short*)(qkvt + (size_t)l * 1280 * KP),
            qkv_b + (size_t)l * TD, qb_g, kb_g, vt_g);
        fattn_kernel<<<dim3(N / 64, H, B), dim3(256), 0, stream>>>(qb_g, kb_g, vt_g, ob);
        // attn-out GEMM + residual -> x
        mm64_kernel<true, true, false, false><<<dim3(4, 64), dim3(256), 0, stream>>>(
            (const unsigned short*)ob, (const unsigned short*)(aot + (size_t)l * 512 * KP),
            attn_out_b + (size_t)l * D, x, x, D, KP);
        // ln2 -> hb
        ln_bf16_kernel<<<dim3(M / 4), dim3(256), 0, stream>>>(x, ln2_w + (size_t)l * D, ln2_b + (size_t)l * D, hb);
        // fc1 + gelu -> ff
        mm64_kernel<true, false, true, true><<<dim3(13, 64), dim3(256), 0, stream>>>(
            (const unsigned short*)hb, (const unsigned short*)(fc1t + (size_t)l * 1664 * KP),
            fc1_b + (size_t)l * FF, nullptr, ff, FF, KP);
        // fc2 GEMM + residual -> x
        mm64_kernel<true, true, false, false><<<dim3(4, 64), dim3(256), 0, stream>>>(
            (const unsigned short*)ff, (const unsigned short*)(fc2t + (size_t)l * 512 * FF),
            fc2_b + (size_t)l * D, x, x, D, FF);
        // next LN (ln1 of l+1, or lnf) -> hb
        const float* nw = (l < L - 1) ? ln1_w + (size_t)(l + 1) * D : lnf_w;
        const float* nb = (l < L - 1) ? ln1_b + (size_t)(l + 1) * D : lnf_b;
        ln_bf16_kernel<<<dim3(M / 4), dim3(256), 0, stream>>>(x, nw, nb, hb);
    }

    // head weight convert + head GEMM (hb holds lnf output)
    wconv_kernel<<<dim3(13, 1000), dim3(32, 8), 0, stream>>>(head_w, headt, D, V, KP, V);
    mmhead_kernel<<<dim3(64, 25), dim3(256), 0, stream>>>(
        (const unsigned short*)hb, (const unsigned short*)headt, out);
}

// Round 17
// 1104.329 us; speedup vs baseline: 1.0095x; 1.0095x over previous
//
#include <hip/hip_runtime.h>
#include <hip/hip_bf16.h>
#include <math.h>

// Problem constants
constexpr int V  = 32000;
constexpr int D  = 400;
constexpr int L  = 6;
constexpr int H  = 8;
constexpr int FF = 1600;
constexpr int B  = 2;
constexpr int N  = 2048;
constexpr int HD = D / H;      // 50
constexpr int TD = 3 * D;      // 1200
constexpr int M  = B * N;      // 4096 rows
constexpr int KP = 416;        // K=400 padded to multiple of 32

typedef __bf16 bf16x8 __attribute__((ext_vector_type(8)));
typedef float  f32x4  __attribute__((ext_vector_type(4)));
typedef unsigned short us16x4 __attribute__((ext_vector_type(4)));

static __device__ __forceinline__ float wave_sum_f(float v) {
#pragma unroll
    for (int m = 32; m; m >>= 1) v += __shfl_xor(v, m, 64);
    return v;
}

static __device__ __forceinline__ void gl_lds16(const unsigned short* g, unsigned short* l) {
    __builtin_amdgcn_global_load_lds(
        (const __attribute__((address_space(1))) unsigned int*)(g),
        (__attribute__((address_space(3))) unsigned int*)(l), 16, 0, 0);
}

static __device__ __forceinline__ unsigned short f2bf(float f) {
    __hip_bfloat16 h = __float2bfloat16(f);
    return *reinterpret_cast<unsigned short*>(&h);
}

// ---------------- embedding + ln1(layer0) fused: writes x fp32 and hb bf16[KP] ----------------
__global__ __launch_bounds__(256) void embed_ln_kernel(const int* __restrict__ idx,
                                                       const float* __restrict__ tok,
                                                       const float* __restrict__ pos,
                                                       const float* __restrict__ lnw,
                                                       const float* __restrict__ lnb,
                                                       float* __restrict__ x,
                                                       __hip_bfloat16* __restrict__ hb) {
    const int row  = blockIdx.x * 4 + (threadIdx.x >> 6);
    const int lane = threadIdx.x & 63;
    const int n = row & (N - 1);
    const float* tr = tok + (size_t)idx[row] * D;
    const float* pr = pos + (size_t)n * D;

    float v[7];
    float s = 0.f, ss = 0.f;
#pragma unroll
    for (int i = 0; i < 7; ++i) {
        const int d = lane + i * 64;
        if (d < D) {
            v[i] = tr[d] + pr[d];
            s += v[i]; ss += v[i] * v[i];
        } else v[i] = 0.f;
    }
    s  = wave_sum_f(s);
    ss = wave_sum_f(ss);
    const float mean = s * (1.0f / D);
    const float var  = ss * (1.0f / D) - mean * mean;
    const float rstd = rsqrtf(var + 1e-5f);

    float* xr = x + (size_t)row * D;
    __hip_bfloat16* hr = hb + (size_t)row * KP;
#pragma unroll
    for (int i = 0; i < 7; ++i) {
        const int d = lane + i * 64;
        if (d < D) {
            xr[d] = v[i];
            hr[d] = __float2bfloat16((v[i] - mean) * rstd * lnw[d] + lnb[d]);
        } else if (d < KP) {
            hr[d] = __float2bfloat16(0.f);
        }
    }
}

// ---------------- LayerNorm fp32 -> bf16 [row][KP] zero-padded; 4 rows/block ----------------
__global__ __launch_bounds__(256) void ln_bf16_kernel(const float* __restrict__ in,
                                                      const float* __restrict__ w,
                                                      const float* __restrict__ b,
                                                      __hip_bfloat16* __restrict__ out) {
    const int row  = blockIdx.x * 4 + (threadIdx.x >> 6);
    const int lane = threadIdx.x & 63;
    const float* xr = in + (size_t)row * D;
    float s = 0.f, ss = 0.f;
    for (int d = lane; d < D; d += 64) {
        float v = xr[d];
        s += v; ss += v * v;
    }
    s  = wave_sum_f(s);
    ss = wave_sum_f(ss);
    float mean = s * (1.0f / D);
    float var  = ss * (1.0f / D) - mean * mean;
    float rstd = rsqrtf(var + 1e-5f);
    __hip_bfloat16* orow = out + (size_t)row * KP;
    for (int d = lane; d < KP; d += 64)
        orow[d] = __float2bfloat16(d < D ? (xr[d] - mean) * rstd * w[d] + b[d] : 0.f);
}

// ---------------- unified weight transpose + fp32->bf16 for the 4 layer-weight tensors ----------------
__global__ __launch_bounds__(256) void wconv_all_kernel(const float* __restrict__ qkv_w,
                                                        const float* __restrict__ ao_w,
                                                        const float* __restrict__ fc1_w,
                                                        const float* __restrict__ fc2_w,
                                                        __hip_bfloat16* __restrict__ qkvt,
                                                        __hip_bfloat16* __restrict__ aot,
                                                        __hip_bfloat16* __restrict__ fc1t,
                                                        __hip_bfloat16* __restrict__ fc2t) {
    const int bid = blockIdx.x;
    int t, rem;
    if      (bid < 3120) { t = 0; rem = bid; }          // qkv: 6 * 13*40
    else if (bid < 4368) { t = 1; rem = bid - 3120; }   // ao : 6 * 13*16
    else if (bid < 8424) { t = 2; rem = bid - 4368; }   // fc1: 6 * 13*52
    else                 { t = 3; rem = bid - 8424; }   // fc2: 6 * 50*16
    const int  tilesPerL[4] = {520, 208, 676, 800};
    const int  nkt[4]  = {13, 13, 13, 50};
    const int  Ka[4]   = {400, 400, 400, 1600};
    const int  Nwa[4]  = {1200, 400, 1600, 400};
    const int  Kpa[4]  = {416, 416, 416, 1600};
    const int  Nra[4]  = {1280, 512, 1664, 512};
    const long sWa[4]  = {480000L, 160000L, 640000L, 640000L};
    const long sBta[4] = {532480L, 212992L, 692224L, 819200L};
    const float* W = t == 0 ? qkv_w : t == 1 ? ao_w : t == 2 ? fc1_w : fc2_w;
    __hip_bfloat16* Bt = t == 0 ? qkvt : t == 1 ? aot : t == 2 ? fc1t : fc2t;
    const int l = rem / tilesPerL[t];
    const int tile = rem % tilesPerL[t];
    const int k0 = (tile % nkt[t]) * 32, n0 = (tile / nkt[t]) * 32;
    const int K = Ka[t], Nw = Nwa[t], Kp = Kpa[t], Nr = Nra[t];

    __shared__ float tt[32][33];
    const float* Wl = W + (size_t)l * sWa[t];
    __hip_bfloat16* Btl = Bt + (size_t)l * sBta[t];
    for (int i = 0; i < 32; i += 8) {
        int k = k0 + threadIdx.y + i, n = n0 + threadIdx.x;
        tt[threadIdx.y + i][threadIdx.x] = (k < K && n < Nw) ? Wl[(size_t)k * Nw + n] : 0.f;
    }
    __syncthreads();
    for (int i = 0; i < 32; i += 8) {
        int n = n0 + threadIdx.y + i, k = k0 + threadIdx.x;
        if (n < Nr && k < Kp) Btl[(size_t)n * Kp + k] = __float2bfloat16(tt[threadIdx.x][threadIdx.y + i]);
    }
}

// ---------------- single-tensor weight transpose (head weight) ----------------
__global__ __launch_bounds__(256) void wconv_kernel(const float* __restrict__ W,
                                                    __hip_bfloat16* __restrict__ Bt,
                                                    int K, int Nw, int Kp, int Nr) {
    __shared__ float t[32][33];
    const int k0 = blockIdx.x * 32, n0 = blockIdx.y * 32;
    for (int i = 0; i < 32; i += 8) {
        int k = k0 + threadIdx.y + i, n = n0 + threadIdx.x;
        t[threadIdx.y + i][threadIdx.x] = (k < K && n < Nw) ? W[(size_t)k * Nw + n] : 0.f;
    }
    __syncthreads();
    for (int i = 0; i < 32; i += 8) {
        int n = n0 + threadIdx.y + i, k = k0 + threadIdx.x;
        if (n < Nr && k < Kp) Bt[(size_t)n * Kp + k] = __float2bfloat16(t[threadIdx.x][threadIdx.y + i]);
    }
}

// ---------------- head GEMM: A-resident LDS, zero-barrier K-loop, B global->reg, NT C-stores ----
// Best measured config (R11/R15: ~305us). Manual pipelines regressed (R12 spill, R13 neutral,
// R14 8-wave); keep compiler-scheduled.
__global__ __launch_bounds__(256) void mmhead_kernel(const unsigned short* __restrict__ A,
                                                     const unsigned short* __restrict__ Bt,
                                                     float* __restrict__ C) {
    __shared__ __align__(1024) unsigned short As[64 * 424];   // 54.3 KB
    const int tid = threadIdx.x, lane = tid & 63, wid = tid >> 6;
    const int wr = wid >> 1, wc = wid & 1;
    const int l15 = lane & 15, g = lane >> 4;

    const int f   = blockIdx.y * 64 + blockIdx.x;   // 0..1599
    const int swz = (f & 7) * 200 + (f >> 3);       // bijective (1600/8=200)
    const int by  = swz & 63;                       // row tile (fast within XCD chunk)
    const int pg  = swz >> 6;                       // panel group 0..24

    // ---- stage A once (coalesced 16B chunks; padded LDS rows) ----
    const unsigned short* Ab = A + (size_t)(by * 64) * KP;
    for (int i = tid; i < 64 * 52; i += 256) {
        const int r = i / 52, c = (i % 52) * 8;
        *(bf16x8*)(As + r * 424 + c) = *(const bf16x8*)(Ab + (size_t)r * KP + c);
    }
    __syncthreads();

    const unsigned short* A0 = As + (wr * 32 + l15) * 424 + g * 8;
    const unsigned short* A1 = A0 + 16 * 424;

#pragma unroll
    for (int p = 0; p < 5; ++p) {
        const int col0 = (pg * 5 + p) * 256 + wc * 128;
        const unsigned short* Bc = Bt + (size_t)col0 * KP + g * 8;
        f32x4 acc[2][8] = {};
#pragma unroll
        for (int ks = 0; ks < 13; ++ks) {
            const int k0 = ks * 32;
            bf16x8 b[8];
#pragma unroll
            for (int n = 0; n < 8; ++n)
                b[n] = *(const bf16x8*)(Bc + (size_t)(n * 16 + l15) * KP + k0);
            const bf16x8 a0 = *(const bf16x8*)(A0 + k0);
            const bf16x8 a1 = *(const bf16x8*)(A1 + k0);
#pragma unroll
            for (int n = 0; n < 8; ++n) {
                acc[0][n] = __builtin_amdgcn_mfma_f32_16x16x32_bf16(a0, b[n], acc[0][n], 0, 0, 0);
                acc[1][n] = __builtin_amdgcn_mfma_f32_16x16x32_bf16(a1, b[n], acc[1][n], 0, 0, 0);
            }
        }
        // ---- store this panel (nontemporal: don't evict B from L2) ----
        const int rowb = by * 64 + wr * 32 + (g << 2);
#pragma unroll
        for (int n = 0; n < 8; ++n) {
            const int col = col0 + n * 16 + l15;
#pragma unroll
            for (int m = 0; m < 2; ++m)
#pragma unroll
                for (int r = 0; r < 4; ++r)
                    __builtin_nontemporal_store(acc[m][n][r], &C[(size_t)(rowb + m * 16 + r) * V + col]);
        }
    }
}

// ---------------- bf16 MFMA GEMM (64x128), DOUBLE-BUFFERED 2-phase (T3 minimum recipe) ----------
// STAGE(next) issued before compute(cur); ONE barrier per K-step (drains prefetch that
// overlapped with MFMA). Same proven pattern as fattn. LDS 24KB.
template <bool BIAS, bool RES, bool GELU, bool OUTBF>
__global__ __launch_bounds__(256) void mm64_kernel(const unsigned short* __restrict__ A,
                                                   const unsigned short* __restrict__ Bt,
                                                   const float* __restrict__ bias,
                                                   const float* __restrict__ res,
                                                   void* __restrict__ Cv,
                                                   int Nc, int Kp) {
    __shared__ __align__(1024) unsigned short As[2][64 * 32];
    __shared__ __align__(1024) unsigned short Bs[2][128 * 32];
    const int tid  = threadIdx.x;
    const int lane = tid & 63, wid = tid >> 6;
    const int wr = wid >> 1, wc = wid & 1;
    const int bx = blockIdx.x, by = blockIdx.y;
    const int l15 = lane & 15, g = lane >> 4;

    f32x4 acc[2][4] = {};

    const unsigned short* Abase = A  + (size_t)(by * 64) * Kp;
    const unsigned short* Bbase = Bt + (size_t)(bx * 128) * Kp;
    const int lrow = lane >> 2;
    const int lcol = (lane & 3) * 8;
    const int nk = Kp >> 5;

#define STG64(buf, kk)                                                                       \
    {                                                                                        \
        const int k0_ = (kk) * 32;                                                           \
        gl_lds16(Abase + (size_t)(wid * 16 + lrow) * Kp + k0_ + lcol, &As[buf][wid * 512]);  \
        _Pragma("unroll")                                                                    \
        for (int c = 0; c < 2; ++c) {                                                        \
            const int chunk = wid * 2 + c;                                                   \
            gl_lds16(Bbase + (size_t)(chunk * 16 + lrow) * Kp + k0_ + lcol,                  \
                     &Bs[buf][chunk * 512]);                                                 \
        }                                                                                    \
    }

    STG64(0, 0);
    __syncthreads();

    for (int t = 0; t < nk; ++t) {
        const int cur = t & 1;
        if (t + 1 < nk) STG64(cur ^ 1, t + 1);
        bf16x8 a[2], b[4];
#pragma unroll
        for (int m = 0; m < 2; ++m)
            a[m] = *(const bf16x8*)(&As[cur][(wr * 32 + m * 16 + l15) * 32 + g * 8]);
#pragma unroll
        for (int n = 0; n < 4; ++n)
            b[n] = *(const bf16x8*)(&Bs[cur][(wc * 64 + n * 16 + l15) * 32 + g * 8]);
#pragma unroll
        for (int m = 0; m < 2; ++m)
#pragma unroll
            for (int n = 0; n < 4; ++n)
                acc[m][n] = __builtin_amdgcn_mfma_f32_16x16x32_bf16(a[m], b[n], acc[m][n], 0, 0, 0);
        __syncthreads();
    }
#undef STG64

    const int col_base = bx * 128 + wc * 64 + l15;
    const int row_base = by * 64 + wr * 32 + (g << 2);
#pragma unroll
    for (int n = 0; n < 4; ++n) {
        const int col = col_base + n * 16;
        if (col >= Nc) continue;
        const float bv = BIAS ? bias[col] : 0.f;
#pragma unroll
        for (int m = 0; m < 2; ++m) {
#pragma unroll
            for (int r = 0; r < 4; ++r) {
                const int row = row_base + m * 16 + r;
                float v = acc[m][n][r] + bv;
                if (GELU) v = 0.5f * v * (1.0f + erff(v * 0.70710678118654752f));
                const size_t ci = (size_t)row * Nc + col;
                if (RES) v += res[ci];
                if (OUTBF) ((__hip_bfloat16*)Cv)[ci] = __float2bfloat16(v);
                else       ((float*)Cv)[ci] = v;
            }
        }
    }
}

// ---------------- qkv GEMM with fused reformat epilogue, DOUBLE-BUFFERED 2-phase ----------------
__global__ __launch_bounds__(256) void mm_qkv_kernel(const unsigned short* __restrict__ A,
                                                     const unsigned short* __restrict__ Bt,
                                                     const float* __restrict__ bias,
                                                     unsigned short* __restrict__ Qb,
                                                     unsigned short* __restrict__ Kb,
                                                     unsigned short* __restrict__ Vt) {
    __shared__ __align__(1024) unsigned short As[2][128 * 32];
    __shared__ __align__(1024) unsigned short Bs[2][128 * 32];
    const int tid  = threadIdx.x;
    const int lane = tid & 63, wid = tid >> 6;
    const int wr = wid >> 1, wc = wid & 1;
    const int bx = blockIdx.x, by = blockIdx.y;

    f32x4 acc[4][4] = {};

    const unsigned short* Abase = A  + (size_t)(by * 128) * KP;
    const unsigned short* Bbase = Bt + (size_t)(bx * 128) * KP;
    const int lrow = lane >> 2;
    const int lcol = (lane & 3) * 8;
    const int nk = KP >> 5;   // 13

#define STGQ(buf, kk)                                                                        \
    {                                                                                        \
        const int k0_ = (kk) * 32;                                                           \
        _Pragma("unroll")                                                                    \
        for (int c = 0; c < 2; ++c) {                                                        \
            const int chunk = wid * 2 + c;                                                   \
            gl_lds16(Abase + (size_t)(chunk * 16 + lrow) * KP + k0_ + lcol,                  \
                     &As[buf][chunk * 512]);                                                 \
            gl_lds16(Bbase + (size_t)(chunk * 16 + lrow) * KP + k0_ + lcol,                  \
                     &Bs[buf][chunk * 512]);                                                 \
        }                                                                                    \
    }

    STGQ(0, 0);
    __syncthreads();

    for (int t = 0; t < nk; ++t) {
        const int cur = t & 1;
        if (t + 1 < nk) STGQ(cur ^ 1, t + 1);
        bf16x8 a[4], b[4];
#pragma unroll
        for (int m = 0; m < 4; ++m)
            a[m] = *(const bf16x8*)(&As[cur][(wr * 64 + m * 16 + (lane & 15)) * 32 + (lane >> 4) * 8]);
#pragma unroll
        for (int n = 0; n < 4; ++n)
            b[n] = *(const bf16x8*)(&Bs[cur][(wc * 64 + n * 16 + (lane & 15)) * 32 + (lane >> 4) * 8]);
#pragma unroll
        for (int m = 0; m < 4; ++m)
#pragma unroll
            for (int n = 0; n < 4; ++n)
                acc[m][n] = __builtin_amdgcn_mfma_f32_16x16x32_bf16(a[m], b[n], acc[m][n], 0, 0, 0);
        __syncthreads();
    }
#undef STGQ

    const float scale = 0.14142135623730950f;  // 1/sqrt(50)
    const int col_base = bx * 128 + wc * 64 + (lane & 15);
    const int row_base = by * 128 + wr * 64 + ((lane >> 4) << 2);
#pragma unroll
    for (int n = 0; n < 4; ++n) {
        const int col = col_base + n * 16;
        if (col >= TD) continue;
        const int part = col < D ? 0 : (col < 2 * D ? 1 : 2);
        const int cc = col - part * D;
        const int h = cc / HD, d = cc % HD;
        const float bv = bias[col];
#pragma unroll
        for (int m = 0; m < 4; ++m) {
            const int row0 = row_base + m * 16;          // multiple of 4, no b-crossing
            const int b = row0 >> 11, nn0 = row0 & (N - 1);
            const int bh = b * H + h;
            if (part == 2) {
                us16x4 pk;
#pragma unroll
                for (int r = 0; r < 4; ++r) pk[r] = f2bf(acc[m][n][r] + bv);
                *(us16x4*)(Vt + (size_t)(bh * 64 + d) * N + nn0) = pk;   // 8B packed store
            } else if (part == 0) {
#pragma unroll
                for (int r = 0; r < 4; ++r)
                    Qb[(size_t)(bh * N + nn0 + r) * 64 + d] = f2bf((acc[m][n][r] + bv) * scale);
            } else {
#pragma unroll
                for (int r = 0; r < 4; ++r)
                    Kb[(size_t)(bh * N + nn0 + r) * 64 + d] = f2bf(acc[m][n][r] + bv);
            }
        }
    }
}

// ---------------- MFMA flash attention: LDS-staged K/V, double-buffered, fixed-max softmax ----------------
__global__ __launch_bounds__(256) void fattn_kernel(const unsigned short* __restrict__ Qb,
                                                    const unsigned short* __restrict__ Kb,
                                                    const unsigned short* __restrict__ Vt,
                                                    __hip_bfloat16* __restrict__ o) {
    const int q0 = blockIdx.x * 64, h = blockIdx.y, b = blockIdx.z;
    const int bh = b * H + h;
    const int tid = threadIdx.x, lane = tid & 63, w = tid >> 6;
    const int l15 = lane & 15, g = lane >> 4;

    __shared__ __align__(1024) unsigned short Ks[2][64 * 64];
    __shared__ __align__(1024) unsigned short Vs[2][64 * 64];
    __shared__ __hip_bfloat16 P_s[4][16 * 72];
    unsigned short* Pw = (unsigned short*)&P_s[w][0];

    const int st_r    = (lane >> 3);
    const int st_cblk = (lane ^ (lane >> 3)) & 7;

    const unsigned short* Qrow = Qb + ((size_t)(bh * N + q0 + w * 16 + l15)) * 64 + g * 8;
    const bf16x8 qa0 = *(const bf16x8*)(Qrow);
    const bf16x8 qa1 = *(const bf16x8*)(Qrow + 32);

    f32x4 acc[4] = {};
    float ssum[4] = {0.f, 0.f, 0.f, 0.f};

    const int nt = q0 / 64 + 1;

#define STAGE(buf, j0)                                                                     \
    {                                                                                      \
        _Pragma("unroll")                                                                  \
        for (int c = 0; c < 2; ++c) {                                                      \
            const int rr = (w * 2 + c) * 8 + st_r;                                         \
            gl_lds16(Kb + (size_t)(bh * N + (j0) + rr) * 64 + st_cblk * 8,                 \
                     &Ks[buf][(w * 2 + c) * 512]);                                         \
            gl_lds16(Vt + (size_t)(bh * 64 + rr) * N + (j0) + st_cblk * 8,                 \
                     &Vs[buf][(w * 2 + c) * 512]);                                         \
        }                                                                                  \
    }

    STAGE(0, 0);
    __syncthreads();

    for (int t = 0; t < nt; ++t) {
        const int cur = t & 1;
        if (t + 1 < nt) STAGE(cur ^ 1, (t + 1) * 64);

        f32x4 s[4];
        const int swz = ((l15 & 7) << 3);
#pragma unroll
        for (int n = 0; n < 4; ++n) {
            const unsigned short* kbase = &Ks[cur][(n * 16 + l15) * 64];
            bf16x8 k0 = *(const bf16x8*)(kbase + ((g * 8) ^ swz));
            bf16x8 k1 = *(const bf16x8*)(kbase + (((g + 4) * 8) ^ swz));
            f32x4 z = {};
            z    = __builtin_amdgcn_mfma_f32_16x16x32_bf16(qa0, k0, z, 0, 0, 0);
            s[n] = __builtin_amdgcn_mfma_f32_16x16x32_bf16(qa1, k1, z, 0, 0, 0);
        }
        if (t == nt - 1) {
#pragma unroll
            for (int n = 0; n < 4; ++n)
#pragma unroll
                for (int r = 0; r < 4; ++r)
                    if (l15 + n * 16 > w * 16 + g * 4 + r) s[n][r] = -INFINITY;
        }
#pragma unroll
        for (int n = 0; n < 4; ++n)
#pragma unroll
            for (int r = 0; r < 4; ++r) {
                float p = __expf(s[n][r]);       // masked -> 0
                ssum[r] += p;
                Pw[(g * 4 + r) * 72 + l15 + n * 16] = f2bf(p);
            }
        bf16x8 pa0 = *(const bf16x8*)(Pw + l15 * 72 + g * 8);
        bf16x8 pa1 = *(const bf16x8*)(Pw + l15 * 72 + 32 + g * 8);

#pragma unroll
        for (int n = 0; n < 4; ++n) {
            const unsigned short* vbase = &Vs[cur][(n * 16 + l15) * 64];
            bf16x8 v0 = *(const bf16x8*)(vbase + ((g * 8) ^ swz));
            bf16x8 v1 = *(const bf16x8*)(vbase + (((g + 4) * 8) ^ swz));
            acc[n] = __builtin_amdgcn_mfma_f32_16x16x32_bf16(pa0, v0, acc[n], 0, 0, 0);
            acc[n] = __builtin_amdgcn_mfma_f32_16x16x32_bf16(pa1, v1, acc[n], 0, 0, 0);
        }

        __syncthreads();
    }
#undef STAGE

#pragma unroll
    for (int r = 0; r < 4; ++r)
#pragma unroll
        for (int msk = 1; msk < 16; msk <<= 1) ssum[r] += __shfl_xor(ssum[r], msk, 64);

#pragma unroll
    for (int n = 0; n < 4; ++n) {
        const int d = n * 16 + l15;
        if (d < HD) {
#pragma unroll
            for (int r = 0; r < 4; ++r) {
                const int row = b * N + q0 + w * 16 + g * 4 + r;
                o[(size_t)row * KP + h * HD + d] = __float2bfloat16(acc[n][r] / ssum[r]);
            }
        }
    }
}

// ---------------- launch ----------------
extern "C" void kernel_launch(void* const* d_in, const int* in_sizes, int n_in,
                              void* d_out, int out_size, void* d_ws, size_t ws_size,
                              hipStream_t stream) {
    const int*   idx        = (const int*)d_in[0];
    const float* tok_emb    = (const float*)d_in[1];
    const float* pos_emb    = (const float*)d_in[2];
    const float* ln1_w      = (const float*)d_in[3];
    const float* ln1_b      = (const float*)d_in[4];
    const float* qkv_w      = (const float*)d_in[5];
    const float* qkv_b      = (const float*)d_in[6];
    const float* attn_out_w = (const float*)d_in[7];
    const float* attn_out_b = (const float*)d_in[8];
    const float* ln2_w      = (const float*)d_in[9];
    const float* ln2_b      = (const float*)d_in[10];
    const float* fc1_w      = (const float*)d_in[11];
    const float* fc1_b      = (const float*)d_in[12];
    const float* fc2_w      = (const float*)d_in[13];
    const float* fc2_b      = (const float*)d_in[14];
    const float* lnf_w      = (const float*)d_in[15];
    const float* lnf_b      = (const float*)d_in[16];
    const float* head_w     = (const float*)d_in[17];
    float* out = (float*)d_out;

    // ---- workspace carve-up (bytes) ----
    char* ws = (char*)d_ws;
    __hip_bfloat16* hb   = (__hip_bfloat16*)(ws);                       // [M][KP] bf16   3,407,872
    float*          x    = (float*)(ws + 3407872);                      // [M][D]  fp32   6,553,600
    __hip_bfloat16* ff   = (__hip_bfloat16*)(ws + 9961472);             // [M][FF] bf16  13,107,200
    __hip_bfloat16* ob   = (__hip_bfloat16*)(ws + 23068672);            // [M][KP] bf16   3,407,872
    __hip_bfloat16* headt = (__hip_bfloat16*)(ws + 3407872);            // [V][KP] bf16 aliases x/ff/ob

    // stash region in d_out (rewritten every call; head GEMM overwrites at the end)
    char* wout = (char*)d_out;
    __hip_bfloat16* qkvt = (__hip_bfloat16*)(wout);                     // 6,389,760
    __hip_bfloat16* aot  = (__hip_bfloat16*)(wout + 6389760);           // 2,555,904
    __hip_bfloat16* fc1t = (__hip_bfloat16*)(wout + 8945664);           // 8,306,688
    __hip_bfloat16* fc2t = (__hip_bfloat16*)(wout + 17252352);          // 9,830,400
    unsigned short* qb_g = (unsigned short*)(wout + 27082752);          // 4,194,304
    unsigned short* kb_g = (unsigned short*)(wout + 31277056);          // 4,194,304
    unsigned short* vt_g = (unsigned short*)(wout + 35471360);          // 4,194,304

    // all layer-weight converts in ONE dispatch
    wconv_all_kernel<<<dim3(13224), dim3(32, 8), 0, stream>>>(
        qkv_w, attn_out_w, fc1_w, fc2_w, qkvt, aot, fc1t, fc2t);

    // embedding + ln1(layer0) fused
    embed_ln_kernel<<<dim3(M / 4), dim3(256), 0, stream>>>(idx, tok_emb, pos_emb, ln1_w, ln1_b, x, hb);
    // pad lanes (d in [50,64)) of Qb/Kb/Vt and pad cols of ob must be zero each call
    hipMemsetAsync(ob, 0, (size_t)M * KP * sizeof(__hip_bfloat16), stream);
    hipMemsetAsync(qb_g, 0, 3 * 4194304, stream);

    for (int l = 0; l < L; ++l) {
        mm_qkv_kernel<<<dim3(10, 32), dim3(256), 0, stream>>>(
            (const unsigned short*)hb, (const unsigned short*)(qkvt + (size_t)l * 1280 * KP),
            qkv_b + (size_t)l * TD, qb_g, kb_g, vt_g);
        fattn_kernel<<<dim3(N / 64, H, B), dim3(256), 0, stream>>>(qb_g, kb_g, vt_g, ob);
        // attn-out GEMM + residual -> x
        mm64_kernel<true, true, false, false><<<dim3(4, 64), dim3(256), 0, stream>>>(
            (const unsigned short*)ob, (const unsigned short*)(aot + (size_t)l * 512 * KP),
            attn_out_b + (size_t)l * D, x, x, D, KP);
        // ln2 -> hb
        ln_bf16_kernel<<<dim3(M / 4), dim3(256), 0, stream>>>(x, ln2_w + (size_t)l * D, ln2_b + (size_t)l * D, hb);
        // fc1 + gelu -> ff
        mm64_kernel<true, false, true, true><<<dim3(13, 64), dim3(256), 0, stream>>>(
            (const unsigned short*)hb, (const unsigned short*)(fc1t + (size_t)l * 1664 * KP),
            fc1_b + (size_t)l * FF, nullptr, ff, FF, KP);
        // fc2 GEMM + residual -> x
        mm64_kernel<true, true, false, false><<<dim3(4, 64), dim3(256), 0, stream>>>(
            (const unsigned short*)ff, (const unsigned short*)(fc2t + (size_t)l * 512 * FF),
            fc2_b + (size_t)l * D, x, x, D, FF);
        // next LN (ln1 of l+1, or lnf) -> hb
        const float* nw = (l < L - 1) ? ln1_w + (size_t)(l + 1) * D : lnf_w;
        const float* nb = (l < L - 1) ? ln1_b + (size_t)(l + 1) * D : lnf_b;
        ln_bf16_kernel<<<dim3(M / 4), dim3(256), 0, stream>>>(x, nw, nb, hb);
    }

    // head weight convert + head GEMM (hb holds lnf output)
    wconv_kernel<<<dim3(13, 1000), dim3(32, 8), 0, stream>>>(head_w, headt, D, V, KP, V);
    mmhead_kernel<<<dim3(64, 25), dim3(256), 0, stream>>>(
        (const unsigned short*)hb, (const unsigned short*)headt, out);
}

// Round 18
// 1093.651 us; speedup vs baseline: 1.0194x; 1.0098x over previous
//
#include <hip/hip_runtime.h>
#include <hip/hip_bf16.h>
#include <math.h>

// Problem constants
constexpr int V  = 32000;
constexpr int D  = 400;
constexpr int L  = 6;
constexpr int H  = 8;
constexpr int FF = 1600;
constexpr int B  = 2;
constexpr int N  = 2048;
constexpr int HD = D / H;      // 50
constexpr int TD = 3 * D;      // 1200
constexpr int M  = B * N;      // 4096 rows
constexpr int KP = 416;        // K=400 padded to multiple of 32

typedef __bf16 bf16x8 __attribute__((ext_vector_type(8)));
typedef float  f32x4  __attribute__((ext_vector_type(4)));
typedef unsigned short us16x4 __attribute__((ext_vector_type(4)));

static __device__ __forceinline__ float wave_sum_f(float v) {
#pragma unroll
    for (int m = 32; m; m >>= 1) v += __shfl_xor(v, m, 64);
    return v;
}

static __device__ __forceinline__ void gl_lds16(const unsigned short* g, unsigned short* l) {
    __builtin_amdgcn_global_load_lds(
        (const __attribute__((address_space(1))) unsigned int*)(g),
        (__attribute__((address_space(3))) unsigned int*)(l), 16, 0, 0);
}

static __device__ __forceinline__ unsigned short f2bf(float f) {
    __hip_bfloat16 h = __float2bfloat16(f);
    return *reinterpret_cast<unsigned short*>(&h);
}

// ---------------- embedding + ln1(layer0) fused: writes x fp32 and hb bf16[KP] ----------------
__global__ __launch_bounds__(256) void embed_ln_kernel(const int* __restrict__ idx,
                                                       const float* __restrict__ tok,
                                                       const float* __restrict__ pos,
                                                       const float* __restrict__ lnw,
                                                       const float* __restrict__ lnb,
                                                       float* __restrict__ x,
                                                       __hip_bfloat16* __restrict__ hb) {
    const int row  = blockIdx.x * 4 + (threadIdx.x >> 6);
    const int lane = threadIdx.x & 63;
    const int n = row & (N - 1);
    const float* tr = tok + (size_t)idx[row] * D;
    const float* pr = pos + (size_t)n * D;

    float v[7];
    float s = 0.f, ss = 0.f;
#pragma unroll
    for (int i = 0; i < 7; ++i) {
        const int d = lane + i * 64;
        if (d < D) {
            v[i] = tr[d] + pr[d];
            s += v[i]; ss += v[i] * v[i];
        } else v[i] = 0.f;
    }
    s  = wave_sum_f(s);
    ss = wave_sum_f(ss);
    const float mean = s * (1.0f / D);
    const float var  = ss * (1.0f / D) - mean * mean;
    const float rstd = rsqrtf(var + 1e-5f);

    float* xr = x + (size_t)row * D;
    __hip_bfloat16* hr = hb + (size_t)row * KP;
#pragma unroll
    for (int i = 0; i < 7; ++i) {
        const int d = lane + i * 64;
        if (d < D) {
            xr[d] = v[i];
            hr[d] = __float2bfloat16((v[i] - mean) * rstd * lnw[d] + lnb[d]);
        } else if (d < KP) {
            hr[d] = __float2bfloat16(0.f);
        }
    }
}

// ---------------- LayerNorm fp32 -> bf16 [row][KP] zero-padded; 4 rows/block ----------------
__global__ __launch_bounds__(256) void ln_bf16_kernel(const float* __restrict__ in,
                                                      const float* __restrict__ w,
                                                      const float* __restrict__ b,
                                                      __hip_bfloat16* __restrict__ out) {
    const int row  = blockIdx.x * 4 + (threadIdx.x >> 6);
    const int lane = threadIdx.x & 63;
    const float* xr = in + (size_t)row * D;
    float s = 0.f, ss = 0.f;
    for (int d = lane; d < D; d += 64) {
        float v = xr[d];
        s += v; ss += v * v;
    }
    s  = wave_sum_f(s);
    ss = wave_sum_f(ss);
    float mean = s * (1.0f / D);
    float var  = ss * (1.0f / D) - mean * mean;
    float rstd = rsqrtf(var + 1e-5f);
    __hip_bfloat16* orow = out + (size_t)row * KP;
    for (int d = lane; d < KP; d += 64)
        orow[d] = __float2bfloat16(d < D ? (xr[d] - mean) * rstd * w[d] + b[d] : 0.f);
}

// ---------------- unified weight transpose + fp32->bf16 for the 4 layer-weight tensors ----------------
__global__ __launch_bounds__(256) void wconv_all_kernel(const float* __restrict__ qkv_w,
                                                        const float* __restrict__ ao_w,
                                                        const float* __restrict__ fc1_w,
                                                        const float* __restrict__ fc2_w,
                                                        __hip_bfloat16* __restrict__ qkvt,
                                                        __hip_bfloat16* __restrict__ aot,
                                                        __hip_bfloat16* __restrict__ fc1t,
                                                        __hip_bfloat16* __restrict__ fc2t) {
    const int bid = blockIdx.x;
    int t, rem;
    if      (bid < 3120) { t = 0; rem = bid; }          // qkv: 6 * 13*40
    else if (bid < 4368) { t = 1; rem = bid - 3120; }   // ao : 6 * 13*16
    else if (bid < 8424) { t = 2; rem = bid - 4368; }   // fc1: 6 * 13*52
    else                 { t = 3; rem = bid - 8424; }   // fc2: 6 * 50*16
    const int  tilesPerL[4] = {520, 208, 676, 800};
    const int  nkt[4]  = {13, 13, 13, 50};
    const int  Ka[4]   = {400, 400, 400, 1600};
    const int  Nwa[4]  = {1200, 400, 1600, 400};
    const int  Kpa[4]  = {416, 416, 416, 1600};
    const int  Nra[4]  = {1280, 512, 1664, 512};
    const long sWa[4]  = {480000L, 160000L, 640000L, 640000L};
    const long sBta[4] = {532480L, 212992L, 692224L, 819200L};
    const float* W = t == 0 ? qkv_w : t == 1 ? ao_w : t == 2 ? fc1_w : fc2_w;
    __hip_bfloat16* Bt = t == 0 ? qkvt : t == 1 ? aot : t == 2 ? fc1t : fc2t;
    const int l = rem / tilesPerL[t];
    const int tile = rem % tilesPerL[t];
    const int k0 = (tile % nkt[t]) * 32, n0 = (tile / nkt[t]) * 32;
    const int K = Ka[t], Nw = Nwa[t], Kp = Kpa[t], Nr = Nra[t];

    __shared__ float tt[32][33];
    const float* Wl = W + (size_t)l * sWa[t];
    __hip_bfloat16* Btl = Bt + (size_t)l * sBta[t];
    for (int i = 0; i < 32; i += 8) {
        int k = k0 + threadIdx.y + i, n = n0 + threadIdx.x;
        tt[threadIdx.y + i][threadIdx.x] = (k < K && n < Nw) ? Wl[(size_t)k * Nw + n] : 0.f;
    }
    __syncthreads();
    for (int i = 0; i < 32; i += 8) {
        int n = n0 + threadIdx.y + i, k = k0 + threadIdx.x;
        if (n < Nr && k < Kp) Btl[(size_t)n * Kp + k] = __float2bfloat16(tt[threadIdx.x][threadIdx.y + i]);
    }
}

// ---------------- single-tensor weight transpose (head weight) ----------------
__global__ __launch_bounds__(256) void wconv_kernel(const float* __restrict__ W,
                                                    __hip_bfloat16* __restrict__ Bt,
                                                    int K, int Nw, int Kp, int Nr) {
    __shared__ float t[32][33];
    const int k0 = blockIdx.x * 32, n0 = blockIdx.y * 32;
    for (int i = 0; i < 32; i += 8) {
        int k = k0 + threadIdx.y + i, n = n0 + threadIdx.x;
        t[threadIdx.y + i][threadIdx.x] = (k < K && n < Nw) ? W[(size_t)k * Nw + n] : 0.f;
    }
    __syncthreads();
    for (int i = 0; i < 32; i += 8) {
        int n = n0 + threadIdx.y + i, k = k0 + threadIdx.x;
        if (n < Nr && k < Kp) Bt[(size_t)n * Kp + k] = __float2bfloat16(t[threadIdx.x][threadIdx.y + i]);
    }
}

// ---------------- head GEMM: A-resident LDS, zero-barrier K-loop, B global->reg, NT C-stores ----
// Best measured config (R11/R15: ~305us). Manual pipelines regressed (R12 spill, R13 neutral,
// R14 8-wave); keep compiler-scheduled.
__global__ __launch_bounds__(256) void mmhead_kernel(const unsigned short* __restrict__ A,
                                                     const unsigned short* __restrict__ Bt,
                                                     float* __restrict__ C) {
    __shared__ __align__(1024) unsigned short As[64 * 424];   // 54.3 KB
    const int tid = threadIdx.x, lane = tid & 63, wid = tid >> 6;
    const int wr = wid >> 1, wc = wid & 1;
    const int l15 = lane & 15, g = lane >> 4;

    const int f   = blockIdx.y * 64 + blockIdx.x;   // 0..1599
    const int swz = (f & 7) * 200 + (f >> 3);       // bijective (1600/8=200)
    const int by  = swz & 63;                       // row tile (fast within XCD chunk)
    const int pg  = swz >> 6;                       // panel group 0..24

    // ---- stage A once (coalesced 16B chunks; padded LDS rows) ----
    const unsigned short* Ab = A + (size_t)(by * 64) * KP;
    for (int i = tid; i < 64 * 52; i += 256) {
        const int r = i / 52, c = (i % 52) * 8;
        *(bf16x8*)(As + r * 424 + c) = *(const bf16x8*)(Ab + (size_t)r * KP + c);
    }
    __syncthreads();

    const unsigned short* A0 = As + (wr * 32 + l15) * 424 + g * 8;
    const unsigned short* A1 = A0 + 16 * 424;

#pragma unroll
    for (int p = 0; p < 5; ++p) {
        const int col0 = (pg * 5 + p) * 256 + wc * 128;
        const unsigned short* Bc = Bt + (size_t)col0 * KP + g * 8;
        f32x4 acc[2][8] = {};
#pragma unroll
        for (int ks = 0; ks < 13; ++ks) {
            const int k0 = ks * 32;
            bf16x8 b[8];
#pragma unroll
            for (int n = 0; n < 8; ++n)
                b[n] = *(const bf16x8*)(Bc + (size_t)(n * 16 + l15) * KP + k0);
            const bf16x8 a0 = *(const bf16x8*)(A0 + k0);
            const bf16x8 a1 = *(const bf16x8*)(A1 + k0);
#pragma unroll
            for (int n = 0; n < 8; ++n) {
                acc[0][n] = __builtin_amdgcn_mfma_f32_16x16x32_bf16(a0, b[n], acc[0][n], 0, 0, 0);
                acc[1][n] = __builtin_amdgcn_mfma_f32_16x16x32_bf16(a1, b[n], acc[1][n], 0, 0, 0);
            }
        }
        // ---- store this panel (nontemporal: don't evict B from L2) ----
        const int rowb = by * 64 + wr * 32 + (g << 2);
#pragma unroll
        for (int n = 0; n < 8; ++n) {
            const int col = col0 + n * 16 + l15;
#pragma unroll
            for (int m = 0; m < 2; ++m)
#pragma unroll
                for (int r = 0; r < 4; ++r)
                    __builtin_nontemporal_store(acc[m][n][r], &C[(size_t)(rowb + m * 16 + r) * V + col]);
        }
    }
}

// ---------------- bf16 MFMA GEMM (64x128), DOUBLE-BUFFERED 2-phase ----------
template <bool BIAS, bool RES, bool GELU, bool OUTBF>
__global__ __launch_bounds__(256) void mm64_kernel(const unsigned short* __restrict__ A,
                                                   const unsigned short* __restrict__ Bt,
                                                   const float* __restrict__ bias,
                                                   const float* __restrict__ res,
                                                   void* __restrict__ Cv,
                                                   int Nc, int Kp) {
    __shared__ __align__(1024) unsigned short As[2][64 * 32];
    __shared__ __align__(1024) unsigned short Bs[2][128 * 32];
    const int tid  = threadIdx.x;
    const int lane = tid & 63, wid = tid >> 6;
    const int wr = wid >> 1, wc = wid & 1;
    const int bx = blockIdx.x, by = blockIdx.y;
    const int l15 = lane & 15, g = lane >> 4;

    f32x4 acc[2][4] = {};

    const unsigned short* Abase = A  + (size_t)(by * 64) * Kp;
    const unsigned short* Bbase = Bt + (size_t)(bx * 128) * Kp;
    const int lrow = lane >> 2;
    const int lcol = (lane & 3) * 8;
    const int nk = Kp >> 5;

#define STG64(buf, kk)                                                                       \
    {                                                                                        \
        const int k0_ = (kk) * 32;                                                           \
        gl_lds16(Abase + (size_t)(wid * 16 + lrow) * Kp + k0_ + lcol, &As[buf][wid * 512]);  \
        _Pragma("unroll")                                                                    \
        for (int c = 0; c < 2; ++c) {                                                        \
            const int chunk = wid * 2 + c;                                                   \
            gl_lds16(Bbase + (size_t)(chunk * 16 + lrow) * Kp + k0_ + lcol,                  \
                     &Bs[buf][chunk * 512]);                                                 \
        }                                                                                    \
    }

    STG64(0, 0);
    __syncthreads();

    for (int t = 0; t < nk; ++t) {
        const int cur = t & 1;
        if (t + 1 < nk) STG64(cur ^ 1, t + 1);
        bf16x8 a[2], b[4];
#pragma unroll
        for (int m = 0; m < 2; ++m)
            a[m] = *(const bf16x8*)(&As[cur][(wr * 32 + m * 16 + l15) * 32 + g * 8]);
#pragma unroll
        for (int n = 0; n < 4; ++n)
            b[n] = *(const bf16x8*)(&Bs[cur][(wc * 64 + n * 16 + l15) * 32 + g * 8]);
#pragma unroll
        for (int m = 0; m < 2; ++m)
#pragma unroll
            for (int n = 0; n < 4; ++n)
                acc[m][n] = __builtin_amdgcn_mfma_f32_16x16x32_bf16(a[m], b[n], acc[m][n], 0, 0, 0);
        __syncthreads();
    }
#undef STG64

    const int col_base = bx * 128 + wc * 64 + l15;
    const int row_base = by * 64 + wr * 32 + (g << 2);
#pragma unroll
    for (int n = 0; n < 4; ++n) {
        const int col = col_base + n * 16;
        if (col >= Nc) continue;
        const float bv = BIAS ? bias[col] : 0.f;
#pragma unroll
        for (int m = 0; m < 2; ++m) {
#pragma unroll
            for (int r = 0; r < 4; ++r) {
                const int row = row_base + m * 16 + r;
                float v = acc[m][n][r] + bv;
                if (GELU) v = 0.5f * v * (1.0f + erff(v * 0.70710678118654752f));
                const size_t ci = (size_t)row * Nc + col;
                if (RES) v += res[ci];
                if (OUTBF) ((__hip_bfloat16*)Cv)[ci] = __float2bfloat16(v);
                else       ((float*)Cv)[ci] = v;
            }
        }
    }
}

// ---------------- qkv GEMM with fused reformat epilogue, DOUBLE-BUFFERED 2-phase ----------------
__global__ __launch_bounds__(256) void mm_qkv_kernel(const unsigned short* __restrict__ A,
                                                     const unsigned short* __restrict__ Bt,
                                                     const float* __restrict__ bias,
                                                     unsigned short* __restrict__ Qb,
                                                     unsigned short* __restrict__ Kb,
                                                     unsigned short* __restrict__ Vt) {
    __shared__ __align__(1024) unsigned short As[2][128 * 32];
    __shared__ __align__(1024) unsigned short Bs[2][128 * 32];
    const int tid  = threadIdx.x;
    const int lane = tid & 63, wid = tid >> 6;
    const int wr = wid >> 1, wc = wid & 1;
    const int bx = blockIdx.x, by = blockIdx.y;

    f32x4 acc[4][4] = {};

    const unsigned short* Abase = A  + (size_t)(by * 128) * KP;
    const unsigned short* Bbase = Bt + (size_t)(bx * 128) * KP;
    const int lrow = lane >> 2;
    const int lcol = (lane & 3) * 8;
    const int nk = KP >> 5;   // 13

#define STGQ(buf, kk)                                                                        \
    {                                                                                        \
        const int k0_ = (kk) * 32;                                                           \
        _Pragma("unroll")                                                                    \
        for (int c = 0; c < 2; ++c) {                                                        \
            const int chunk = wid * 2 + c;                                                   \
            gl_lds16(Abase + (size_t)(chunk * 16 + lrow) * KP + k0_ + lcol,                  \
                     &As[buf][chunk * 512]);                                                 \
            gl_lds16(Bbase + (size_t)(chunk * 16 + lrow) * KP + k0_ + lcol,                  \
                     &Bs[buf][chunk * 512]);                                                 \
        }                                                                                    \
    }

    STGQ(0, 0);
    __syncthreads();

    for (int t = 0; t < nk; ++t) {
        const int cur = t & 1;
        if (t + 1 < nk) STGQ(cur ^ 1, t + 1);
        bf16x8 a[4], b[4];
#pragma unroll
        for (int m = 0; m < 4; ++m)
            a[m] = *(const bf16x8*)(&As[cur][(wr * 64 + m * 16 + (lane & 15)) * 32 + (lane >> 4) * 8]);
#pragma unroll
        for (int n = 0; n < 4; ++n)
            b[n] = *(const bf16x8*)(&Bs[cur][(wc * 64 + n * 16 + (lane & 15)) * 32 + (lane >> 4) * 8]);
#pragma unroll
        for (int m = 0; m < 4; ++m)
#pragma unroll
            for (int n = 0; n < 4; ++n)
                acc[m][n] = __builtin_amdgcn_mfma_f32_16x16x32_bf16(a[m], b[n], acc[m][n], 0, 0, 0);
        __syncthreads();
    }
#undef STGQ

    const float scale = 0.14142135623730950f;  // 1/sqrt(50)
    const int col_base = bx * 128 + wc * 64 + (lane & 15);
    const int row_base = by * 128 + wr * 64 + ((lane >> 4) << 2);
#pragma unroll
    for (int n = 0; n < 4; ++n) {
        const int col = col_base + n * 16;
        if (col >= TD) continue;
        const int part = col < D ? 0 : (col < 2 * D ? 1 : 2);
        const int cc = col - part * D;
        const int h = cc / HD, d = cc % HD;
        const float bv = bias[col];
#pragma unroll
        for (int m = 0; m < 4; ++m) {
            const int row0 = row_base + m * 16;          // multiple of 4, no b-crossing
            const int b = row0 >> 11, nn0 = row0 & (N - 1);
            const int bh = b * H + h;
            if (part == 2) {
                us16x4 pk;
#pragma unroll
                for (int r = 0; r < 4; ++r) pk[r] = f2bf(acc[m][n][r] + bv);
                *(us16x4*)(Vt + (size_t)(bh * 64 + d) * N + nn0) = pk;   // 8B packed store
            } else if (part == 0) {
#pragma unroll
                for (int r = 0; r < 4; ++r)
                    Qb[(size_t)(bh * N + nn0 + r) * 64 + d] = f2bf((acc[m][n][r] + bv) * scale);
            } else {
#pragma unroll
                for (int r = 0; r < 4; ++r)
                    Kb[(size_t)(bh * N + nn0 + r) * 64 + d] = f2bf(acc[m][n][r] + bv);
            }
        }
    }
}

// ---------------- MFMA flash attention, TRIANGLE-PAIRED: block i handles q-chunks i and 31-i ----
// Causal work per q-chunk i is (i+1) K-chunks; pairing (i, 31-i) gives every block exactly 33
// chunk-units -> perfect load balance at 256 blocks (1/CU), kills the straggler tail of the
// old 512-block imbalanced grid.
__global__ __launch_bounds__(256) void fattn_kernel(const unsigned short* __restrict__ Qb,
                                                    const unsigned short* __restrict__ Kb,
                                                    const unsigned short* __restrict__ Vt,
                                                    __hip_bfloat16* __restrict__ o) {
    const int h = blockIdx.y, b = blockIdx.z;
    const int bh = b * H + h;
    const int tid = threadIdx.x, lane = tid & 63, w = tid >> 6;
    const int l15 = lane & 15, g = lane >> 4;
    const int NQ = N / 64;   // 32

    __shared__ __align__(1024) unsigned short Ks[2][64 * 64];
    __shared__ __align__(1024) unsigned short Vs[2][64 * 64];
    __shared__ __hip_bfloat16 P_s[4][16 * 72];
    unsigned short* Pw = (unsigned short*)&P_s[w][0];

    const int st_r    = (lane >> 3);
    const int st_cblk = (lane ^ (lane >> 3)) & 7;

#define STAGE(buf, j0)                                                                     \
    {                                                                                      \
        _Pragma("unroll")                                                                  \
        for (int c = 0; c < 2; ++c) {                                                      \
            const int rr = (w * 2 + c) * 8 + st_r;                                         \
            gl_lds16(Kb + (size_t)(bh * N + (j0) + rr) * 64 + st_cblk * 8,                 \
                     &Ks[buf][(w * 2 + c) * 512]);                                         \
            gl_lds16(Vt + (size_t)(bh * 64 + rr) * N + (j0) + st_cblk * 8,                 \
                     &Vs[buf][(w * 2 + c) * 512]);                                         \
        }                                                                                  \
    }

    for (int pass = 0; pass < 2; ++pass) {
        const int qc = pass == 0 ? (int)blockIdx.x : (NQ - 1 - (int)blockIdx.x);
        const int q0 = qc * 64;

        const unsigned short* Qrow = Qb + ((size_t)(bh * N + q0 + w * 16 + l15)) * 64 + g * 8;
        const bf16x8 qa0 = *(const bf16x8*)(Qrow);
        const bf16x8 qa1 = *(const bf16x8*)(Qrow + 32);

        f32x4 acc[4] = {};
        float ssum[4] = {0.f, 0.f, 0.f, 0.f};
        const int nt = qc + 1;

        STAGE(0, 0);
        __syncthreads();

        for (int t = 0; t < nt; ++t) {
            const int cur = t & 1;
            if (t + 1 < nt) STAGE(cur ^ 1, (t + 1) * 64);

            f32x4 s[4];
            const int swz = ((l15 & 7) << 3);
#pragma unroll
            for (int n = 0; n < 4; ++n) {
                const unsigned short* kbase = &Ks[cur][(n * 16 + l15) * 64];
                bf16x8 k0 = *(const bf16x8*)(kbase + ((g * 8) ^ swz));
                bf16x8 k1 = *(const bf16x8*)(kbase + (((g + 4) * 8) ^ swz));
                f32x4 z = {};
                z    = __builtin_amdgcn_mfma_f32_16x16x32_bf16(qa0, k0, z, 0, 0, 0);
                s[n] = __builtin_amdgcn_mfma_f32_16x16x32_bf16(qa1, k1, z, 0, 0, 0);
            }
            if (t == nt - 1) {
#pragma unroll
                for (int n = 0; n < 4; ++n)
#pragma unroll
                    for (int r = 0; r < 4; ++r)
                        if (l15 + n * 16 > w * 16 + g * 4 + r) s[n][r] = -INFINITY;
            }
#pragma unroll
            for (int n = 0; n < 4; ++n)
#pragma unroll
                for (int r = 0; r < 4; ++r) {
                    float p = __expf(s[n][r]);       // masked -> 0
                    ssum[r] += p;
                    Pw[(g * 4 + r) * 72 + l15 + n * 16] = f2bf(p);
                }
            bf16x8 pa0 = *(const bf16x8*)(Pw + l15 * 72 + g * 8);
            bf16x8 pa1 = *(const bf16x8*)(Pw + l15 * 72 + 32 + g * 8);

#pragma unroll
            for (int n = 0; n < 4; ++n) {
                const unsigned short* vbase = &Vs[cur][(n * 16 + l15) * 64];
                bf16x8 v0 = *(const bf16x8*)(vbase + ((g * 8) ^ swz));
                bf16x8 v1 = *(const bf16x8*)(vbase + (((g + 4) * 8) ^ swz));
                acc[n] = __builtin_amdgcn_mfma_f32_16x16x32_bf16(pa0, v0, acc[n], 0, 0, 0);
                acc[n] = __builtin_amdgcn_mfma_f32_16x16x32_bf16(pa1, v1, acc[n], 0, 0, 0);
            }

            __syncthreads();
        }

#pragma unroll
        for (int r = 0; r < 4; ++r)
#pragma unroll
            for (int msk = 1; msk < 16; msk <<= 1) ssum[r] += __shfl_xor(ssum[r], msk, 64);

#pragma unroll
        for (int n = 0; n < 4; ++n) {
            const int d = n * 16 + l15;
            if (d < HD) {
#pragma unroll
                for (int r = 0; r < 4; ++r) {
                    const int row = b * N + q0 + w * 16 + g * 4 + r;
                    o[(size_t)row * KP + h * HD + d] = __float2bfloat16(acc[n][r] / ssum[r]);
                }
            }
        }
    }
#undef STAGE
}

// ---------------- launch ----------------
extern "C" void kernel_launch(void* const* d_in, const int* in_sizes, int n_in,
                              void* d_out, int out_size, void* d_ws, size_t ws_size,
                              hipStream_t stream) {
    const int*   idx        = (const int*)d_in[0];
    const float* tok_emb    = (const float*)d_in[1];
    const float* pos_emb    = (const float*)d_in[2];
    const float* ln1_w      = (const float*)d_in[3];
    const float* ln1_b      = (const float*)d_in[4];
    const float* qkv_w      = (const float*)d_in[5];
    const float* qkv_b      = (const float*)d_in[6];
    const float* attn_out_w = (const float*)d_in[7];
    const float* attn_out_b = (const float*)d_in[8];
    const float* ln2_w      = (const float*)d_in[9];
    const float* ln2_b      = (const float*)d_in[10];
    const float* fc1_w      = (const float*)d_in[11];
    const float* fc1_b      = (const float*)d_in[12];
    const float* fc2_w      = (const float*)d_in[13];
    const float* fc2_b      = (const float*)d_in[14];
    const float* lnf_w      = (const float*)d_in[15];
    const float* lnf_b      = (const float*)d_in[16];
    const float* head_w     = (const float*)d_in[17];
    float* out = (float*)d_out;

    // ---- workspace carve-up (bytes) ----
    char* ws = (char*)d_ws;
    __hip_bfloat16* hb   = (__hip_bfloat16*)(ws);                       // [M][KP] bf16   3,407,872
    float*          x    = (float*)(ws + 3407872);                      // [M][D]  fp32   6,553,600
    __hip_bfloat16* ff   = (__hip_bfloat16*)(ws + 9961472);             // [M][FF] bf16  13,107,200
    __hip_bfloat16* ob   = (__hip_bfloat16*)(ws + 23068672);            // [M][KP] bf16   3,407,872
    __hip_bfloat16* headt = (__hip_bfloat16*)(ws + 3407872);            // [V][KP] bf16 aliases x/ff/ob

    // stash region in d_out (rewritten every call; head GEMM overwrites at the end)
    char* wout = (char*)d_out;
    __hip_bfloat16* qkvt = (__hip_bfloat16*)(wout);                     // 6,389,760
    __hip_bfloat16* aot  = (__hip_bfloat16*)(wout + 6389760);           // 2,555,904
    __hip_bfloat16* fc1t = (__hip_bfloat16*)(wout + 8945664);           // 8,306,688
    __hip_bfloat16* fc2t = (__hip_bfloat16*)(wout + 17252352);          // 9,830,400
    unsigned short* qb_g = (unsigned short*)(wout + 27082752);          // 4,194,304
    unsigned short* kb_g = (unsigned short*)(wout + 31277056);          // 4,194,304
    unsigned short* vt_g = (unsigned short*)(wout + 35471360);          // 4,194,304

    // all layer-weight converts in ONE dispatch
    wconv_all_kernel<<<dim3(13224), dim3(32, 8), 0, stream>>>(
        qkv_w, attn_out_w, fc1_w, fc2_w, qkvt, aot, fc1t, fc2t);

    // embedding + ln1(layer0) fused
    embed_ln_kernel<<<dim3(M / 4), dim3(256), 0, stream>>>(idx, tok_emb, pos_emb, ln1_w, ln1_b, x, hb);
    // pad lanes (d in [50,64)) of Qb/Kb/Vt and pad cols of ob must be zero each call
    hipMemsetAsync(ob, 0, (size_t)M * KP * sizeof(__hip_bfloat16), stream);
    hipMemsetAsync(qb_g, 0, 3 * 4194304, stream);

    for (int l = 0; l < L; ++l) {
        mm_qkv_kernel<<<dim3(10, 32), dim3(256), 0, stream>>>(
            (const unsigned short*)hb, (const unsigned short*)(qkvt + (size_t)l * 1280 * KP),
            qkv_b + (size_t)l * TD, qb_g, kb_g, vt_g);
        fattn_kernel<<<dim3(N / 128, H, B), dim3(256), 0, stream>>>(qb_g, kb_g, vt_g, ob);
        // attn-out GEMM + residual -> x
        mm64_kernel<true, true, false, false><<<dim3(4, 64), dim3(256), 0, stream>>>(
            (const unsigned short*)ob, (const unsigned short*)(aot + (size_t)l * 512 * KP),
            attn_out_b + (size_t)l * D, x, x, D, KP);
        // ln2 -> hb
        ln_bf16_kernel<<<dim3(M / 4), dim3(256), 0, stream>>>(x, ln2_w + (size_t)l * D, ln2_b + (size_t)l * D, hb);
        // fc1 + gelu -> ff
        mm64_kernel<true, false, true, true><<<dim3(13, 64), dim3(256), 0, stream>>>(
            (const unsigned short*)hb, (const unsigned short*)(fc1t + (size_t)l * 1664 * KP),
            fc1_b + (size_t)l * FF, nullptr, ff, FF, KP);
        // fc2 GEMM + residual -> x
        mm64_kernel<true, true, false, false><<<dim3(4, 64), dim3(256), 0, stream>>>(
            (const unsigned short*)ff, (const unsigned short*)(fc2t + (size_t)l * 512 * FF),
            fc2_b + (size_t)l * D, x, x, D, FF);
        // next LN (ln1 of l+1, or lnf) -> hb
        const float* nw = (l < L - 1) ? ln1_w + (size_t)(l + 1) * D : lnf_w;
        const float* nb = (l < L - 1) ? ln1_b + (size_t)(l + 1) * D : lnf_b;
        ln_bf16_kernel<<<dim3(M / 4), dim3(256), 0, stream>>>(x, nw, nb, hb);
    }

    // head weight convert + head GEMM (hb holds lnf output)
    wconv_kernel<<<dim3(13, 1000), dim3(32, 8), 0, stream>>>(head_w, headt, D, V, KP, V);
    mmhead_kernel<<<dim3(64, 25), dim3(256), 0, stream>>>(
        (const unsigned short*)hb, (const unsigned short*)headt, out);
}